// Round 6
// baseline (190.369 us; speedup 1.0000x reference)
//
#include <hip/hip_runtime.h>

#define LAMC    10000.0f
#define INV_LAM 1e-4f
#define EPSC    1e-12f
#define TOLC    1e-6f
#define BLK     256
#define WPB     (BLK / 64)       // waves per block
#define PPT     4                // pairs per thread
#define RPW     (64 * 2 * PPT)   // rows per wave  = 512
#define RPB     (BLK * 2 * PPT)  // rows per block = 2048

__device__ __forceinline__ float frcp(float x)  { return __builtin_amdgcn_rcpf(x); }
__device__ __forceinline__ float frsq(float x)  { return __builtin_amdgcn_rsqf(x); }
__device__ __forceinline__ float fsqrt_(float x){ return __builtin_amdgcn_sqrtf(x); }

// sign(phi(t)) without sqrt/div: phi = L - R*sqrt(q), q >= EPS > 0
__device__ __forceinline__ bool phi_pos(float t, float A, float p, float N, float b) {
    float q  = fmaxf(fmaf(t, fmaf(t, A, -2.0f * p), N), EPSC);
    float L  = fmaf(-t, A, p);        // p - t*A   (U_MAX = 1)
    float R  = fmaf(t, INV_LAM, b);   // b + t/LAM
    float L2 = L * L;
    float Rq = (R * R) * q;
    return (R < 0.0f) ? ((L >= 0.0f) || (L2 < Rq))
                      : ((L >  0.0f) && (L2 > Rq));
}

// 4 independent heavy rows solved with interleaved dependency chains (ILP).
// Per-row algorithm is EXACTLY R5's (passing) one:
//  bracket rows: 8 geometric bisections + 5 safeguarded clamped Newtons;
//  collapse rows (phi(0)<=0): 3 unclamped Newtons from 0, frozen after.
__device__ __forceinline__ void heavy_solve4(const float ux[4], const float uy[4],
                                             const float ax[4], const float ay[4],
                                             const float bb[4], float2 res[4]) {
    float A[4], p[4], N[4], t3[4], lo[4], hi[4];
    bool  br[4];
    #pragma unroll
    for (int r = 0; r < 4; ++r) {
        A[r] = fmaf(ax[r], ax[r], ay[r] * ay[r]);
        p[r] = fmaf(ax[r], ux[r], ay[r] * uy[r]);
        N[r] = fmaf(ux[r], ux[r], uy[r] * uy[r]);
        br[r] = phi_pos(0.0f, A[r], p[r], N[r], bb[r]);
        float tA = p[r] * frcp(fmaxf(A[r], 1e-30f));
        bool hiTA = (p[r] > 0.0f) && (fmaf(tA, INV_LAM, bb[r]) >= 0.0f);
        bool loTA = (p[r] > 0.0f) && !hiTA;
        float l = loTA ? tA : 0.0f;
        float h = hiTA ? tA : -LAMC * bb[r];
        lo[r] = br[r] ? l : 0.0f;
        hi[r] = br[r] ? h : 0.0f;
        t3[r] = 0.0f;
    }
    #pragma unroll 1
    for (int k = 0; k < 8; ++k) {            // geometric bisection, 4-way ILP
        #pragma unroll
        for (int r = 0; r < 4; ++r) {
            float fl  = fmaxf(lo[r], 1e-6f * hi[r]);
            float mid = fsqrt_(fl * hi[r]);
            bool pos  = phi_pos(mid, A[r], p[r], N[r], bb[r]);
            lo[r] = pos ? mid : lo[r];
            hi[r] = pos ? hi[r] : mid;
        }
    }
    #pragma unroll
    for (int r = 0; r < 4; ++r) t3[r] = br[r] ? 0.5f * (lo[r] + hi[r]) : 0.0f;
    #pragma unroll 1
    for (int it = 0; it < 5; ++it) {         // Newton, 4-way ILP
        #pragma unroll
        for (int r = 0; r < 4; ++r) {
            float q   = fmaxf(fmaf(t3[r], fmaf(t3[r], A[r], -2.0f * p[r]), N[r]), EPSC);
            float nrm = fsqrt_(q);
            float R   = fmaf(t3[r], INV_LAM, bb[r]);
            float f   = fmaf(-t3[r], A[r], p[r]) - R * nrm;
            float df  = -A[r] - nrm * INV_LAM - R * fmaf(t3[r], A[r], -p[r]) * frcp(nrm);
            df = (fabsf(df) > 1e-8f) ? df : -1e-8f;
            bool fp = f > 0.0f;              // phi(t3)>0 -> root above t3
            lo[r] = (br[r] && fp)  ? t3[r] : lo[r];
            hi[r] = (br[r] && !fp) ? t3[r] : hi[r];
            float tn   = t3[r] - f * frcp(df);
            float tb   = fminf(fmaxf(tn, lo[r]), hi[r]);
            float tupd = br[r] ? tb : tn;    // collapse rows: unclamped
            t3[r] = (!br[r] && it >= 3) ? t3[r] : tupd;  // freeze collapse after 3
        }
    }
    #pragma unroll
    for (int r = 0; r < 4; ++r) {
        float q3  = fmaxf(fmaf(t3[r], fmaf(t3[r], A[r], -2.0f * p[r]), N[r]), EPSC);
        float k3  = fmaxf(fsqrt_(q3), 1.0f);
        float inv = frcp(k3);
        res[r] = make_float2(fmaf(-t3[r], ax[r], ux[r]) * inv,
                             fmaf(-t3[r], ay[r], uy[r]) * inv);
    }
}

// branchless easy path; a,b precomputed. returns true if heavy (branch 3).
__device__ __forceinline__ bool easy_row(float ux, float uy,
                                         float ax, float ay, float b,
                                         float& ox, float& oy) {
    float A  = fmaf(ax, ax, ay * ay);
    float p  = fmaf(ax, ux, ay * uy);
    float N  = fmaf(ux, ux, uy * uy);
    float s1 = fminf(1.0f, frsq(fmaxf(N, EPSC)));   // min(1, 1/|u|)
    float u1x = ux * s1, u1y = uy * s1;
    bool feas1 = fmaf(ax, u1x, ay * u1y) <= b + TOLC;
    float t2  = LAMC * (p - b) * frcp(fmaf(LAMC, A, 1.0f));
    float u2x = fmaf(-t2, ax, ux), u2y = fmaf(-t2, ay, uy);
    bool ok2 = (t2 >= -TOLC) && (fmaf(u2x, u2x, u2y * u2y) <= 1.0f + TOLC);
    ox = feas1 ? u1x : u2x;
    oy = feas1 ? u1y : u2y;
    return !feas1 && !ok2;
}

__global__ __launch_bounds__(BLK) void cbf_kernel(const float4* __restrict__ u4,
                                                  const float4* __restrict__ obs4,
                                                  const float2* __restrict__ u2v,
                                                  const float*  __restrict__ obs,
                                                  float4* __restrict__ out4,
                                                  int npair) {
    __shared__ short  sid [WPB][RPW];   // wave-local heavy worklist (local row ids)
    __shared__ float2 sres[WPB][RPW];   // heavy results by slot

    int tid  = threadIdx.x;
    int wave = tid >> 6;
    int lane = tid & 63;
    unsigned long long ltmask = (1ull << lane) - 1ull;
    int pairbase = blockIdx.x * (BLK * PPT);

    float4 r[PPT];
    bool   hv[2 * PPT];
    bool   valid[PPT];

    #pragma unroll
    for (int k = 0; k < PPT; ++k) {
        int i = pairbase + k * BLK + tid;
        valid[k] = i < npair;
        float4 z  = make_float4(0.f, 0.f, 0.f, 0.f);
        float4 uu = valid[k] ? u4[i]          : z;
        float4 o0 = valid[k] ? obs4[3 * i + 0] : z;
        float4 o1 = valid[k] ? obs4[3 * i + 1] : z;
        float4 o2 = valid[k] ? obs4[3 * i + 2] : z;
        // row 2i:   p=(o0.z,o0.w)  v=(o1.x,o1.y)
        // row 2i+1: p=(o2.x,o2.y)  v=(o2.z,o2.w)
        float ax0 = -2.0f * o0.z, ay0 = -2.0f * o0.w;
        float b0  = fmaf(2.0f, fmaf(o0.z, o0.z, o0.w * o0.w) - 1.0f,
                         -2.0f * fmaf(o0.z, o1.x, o0.w * o1.y));
        float ax1 = -2.0f * o2.x, ay1 = -2.0f * o2.y;
        float b1  = fmaf(2.0f, fmaf(o2.x, o2.x, o2.y * o2.y) - 1.0f,
                         -2.0f * fmaf(o2.x, o2.z, o2.y * o2.w));
        r[k] = z;
        hv[2 * k]     = valid[k] && easy_row(uu.x, uu.y, ax0, ay0, b0, r[k].x, r[k].y);
        hv[2 * k + 1] = valid[k] && easy_row(uu.z, uu.w, ax1, ay1, b1, r[k].z, r[k].w);
    }

    // wave-local ballot compaction (8 row-classes), slots remembered in regs
    int tot = 0;
    int slot[2 * PPT];
    #pragma unroll
    for (int m = 0; m < 2 * PPT; ++m) {
        unsigned long long mm = __ballot(hv[m]);
        slot[m] = tot + __popcll(mm & ltmask);
        if (hv[m]) {
            int k  = m >> 1;
            int lr = 2 * (k * BLK + tid) + (m & 1);   // block-local row id < 2048
            sid[wave][slot[m]] = (short)lr;
        }
        tot += __popcll(mm);
    }
    __threadfence_block();   // wave lockstep + lgkmcnt drain orders LDS w->r

    // heavy batches: 4 rows per lane, solved with interleaved chains
    #pragma unroll 1
    for (int base = 0; base < tot; base += 256) {
        float hux[4], huy[4], hax[4], hay[4], hbb[4];
        float2 hres[4];
        int jj[4];
        #pragma unroll
        for (int q = 0; q < 4; ++q) {
            int j  = base + q * 64 + lane;
            jj[q]  = j;
            int js = (j < tot) ? j : (tot - 1);        // clamp: duplicate work, no store
            int lr = sid[wave][js];
            int gr = blockIdx.x * RPB + lr;
            float2 uu = u2v[gr];                       // L2/L3-hot re-reads
            float2 pr = *(const float2*)(obs + 6 * gr + 2);
            float2 vv = *(const float2*)(obs + 6 * gr + 4);
            hux[q] = uu.x;  huy[q] = uu.y;
            hax[q] = -2.0f * pr.x;  hay[q] = -2.0f * pr.y;
            hbb[q] = fmaf(2.0f, fmaf(pr.x, pr.x, pr.y * pr.y) - 1.0f,
                          -2.0f * fmaf(pr.x, vv.x, pr.y * vv.y));
        }
        heavy_solve4(hux, huy, hax, hay, hbb, hres);
        #pragma unroll
        for (int q = 0; q < 4; ++q)
            if (jj[q] < tot) sres[wave][jj[q]] = hres[q];
    }
    __threadfence_block();

    #pragma unroll
    for (int m = 0; m < 2 * PPT; ++m) {
        if (hv[m]) {
            float2 s = sres[wave][slot[m]];
            int k = m >> 1;
            if (m & 1) { r[k].z = s.x; r[k].w = s.y; }
            else       { r[k].x = s.x; r[k].y = s.y; }
        }
    }
    #pragma unroll
    for (int k = 0; k < PPT; ++k) {
        int i = pairbase + k * BLK + tid;
        if (valid[k]) out4[i] = r[k];
    }
}

extern "C" void kernel_launch(void* const* d_in, const int* in_sizes, int n_in,
                              void* d_out, int out_size, void* d_ws, size_t ws_size,
                              hipStream_t stream) {
    const float* u_nom = (const float*)d_in[0];
    const float* obs   = (const float*)d_in[1];
    float* out = (float*)d_out;
    int rows   = in_sizes[0] / 2;             // B
    int npair  = rows / 2;                    // 2 rows per thread-slot
    int blocks = (npair + BLK * PPT - 1) / (BLK * PPT);
    cbf_kernel<<<blocks, BLK, 0, stream>>>((const float4*)u_nom,
                                           (const float4*)obs,
                                           (const float2*)u_nom, obs,
                                           (float4*)out, npair);
}

// Round 7
// 181.639 us; speedup vs baseline: 1.0481x; 1.0481x over previous
//
#include <hip/hip_runtime.h>

#define LAMC    10000.0f
#define INV_LAM 1e-4f
#define EPSC    1e-12f
#define TOLC    1e-6f
#define BLK     256
#define WPB     (BLK / 64)       // waves per block
#define PPT     2                // pairs per thread
#define RPW     (64 * 2 * PPT)   // rows per wave  = 256
#define RPB     (BLK * 2 * PPT)  // rows per block = 1024

__device__ __forceinline__ float frcp(float x)  { return __builtin_amdgcn_rcpf(x); }
__device__ __forceinline__ float frsq(float x)  { return __builtin_amdgcn_rsqf(x); }
__device__ __forceinline__ float fsqrt_(float x){ return __builtin_amdgcn_sqrtf(x); }

// sign(phi(t)) without sqrt/div: phi = L - R*sqrt(q), q >= EPS > 0
__device__ __forceinline__ bool phi_pos(float t, float A, float p, float N, float b) {
    float q  = fmaxf(fmaf(t, fmaf(t, A, -2.0f * p), N), EPSC);
    float L  = fmaf(-t, A, p);        // p - t*A   (U_MAX = 1)
    float R  = fmaf(t, INV_LAM, b);   // b + t/LAM
    float L2 = L * L;
    float Rq = (R * R) * q;
    return (R < 0.0f) ? ((L >= 0.0f) || (L2 < Rq))
                      : ((L >  0.0f) && (L2 > Rq));
}

// 2 independent heavy rows solved with interleaved dependency chains (ILP).
// Per-row algorithm is EXACTLY the R6-verified one:
//  bracket rows: 8 geometric bisections + 5 safeguarded clamped Newtons;
//  collapse rows (phi(0)<=0): 3 unclamped Newtons from 0, frozen after.
__device__ __forceinline__ void heavy_solve2(const float ux[2], const float uy[2],
                                             const float ax[2], const float ay[2],
                                             const float bb[2], float2 res[2]) {
    float A[2], p[2], N[2], t3[2], lo[2], hi[2];
    bool  br[2];
    #pragma unroll
    for (int r = 0; r < 2; ++r) {
        A[r] = fmaf(ax[r], ax[r], ay[r] * ay[r]);
        p[r] = fmaf(ax[r], ux[r], ay[r] * uy[r]);
        N[r] = fmaf(ux[r], ux[r], uy[r] * uy[r]);
        br[r] = phi_pos(0.0f, A[r], p[r], N[r], bb[r]);
        float tA = p[r] * frcp(fmaxf(A[r], 1e-30f));
        bool hiTA = (p[r] > 0.0f) && (fmaf(tA, INV_LAM, bb[r]) >= 0.0f);
        bool loTA = (p[r] > 0.0f) && !hiTA;
        float l = loTA ? tA : 0.0f;
        float h = hiTA ? tA : -LAMC * bb[r];
        lo[r] = br[r] ? l : 0.0f;
        hi[r] = br[r] ? h : 0.0f;
        t3[r] = 0.0f;
    }
    #pragma unroll 1
    for (int k = 0; k < 8; ++k) {            // geometric bisection, 2-way ILP
        #pragma unroll
        for (int r = 0; r < 2; ++r) {
            float fl  = fmaxf(lo[r], 1e-6f * hi[r]);
            float mid = fsqrt_(fl * hi[r]);
            bool pos  = phi_pos(mid, A[r], p[r], N[r], bb[r]);
            lo[r] = pos ? mid : lo[r];
            hi[r] = pos ? hi[r] : mid;
        }
    }
    #pragma unroll
    for (int r = 0; r < 2; ++r) t3[r] = br[r] ? 0.5f * (lo[r] + hi[r]) : 0.0f;
    #pragma unroll 1
    for (int it = 0; it < 5; ++it) {         // Newton, 2-way ILP
        #pragma unroll
        for (int r = 0; r < 2; ++r) {
            float q   = fmaxf(fmaf(t3[r], fmaf(t3[r], A[r], -2.0f * p[r]), N[r]), EPSC);
            float nrm = fsqrt_(q);
            float R   = fmaf(t3[r], INV_LAM, bb[r]);
            float f   = fmaf(-t3[r], A[r], p[r]) - R * nrm;
            float df  = -A[r] - nrm * INV_LAM - R * fmaf(t3[r], A[r], -p[r]) * frcp(nrm);
            df = (fabsf(df) > 1e-8f) ? df : -1e-8f;
            bool fp = f > 0.0f;              // phi(t3)>0 -> root above t3
            lo[r] = (br[r] && fp)  ? t3[r] : lo[r];
            hi[r] = (br[r] && !fp) ? t3[r] : hi[r];
            float tn   = t3[r] - f * frcp(df);
            float tb   = fminf(fmaxf(tn, lo[r]), hi[r]);
            float tupd = br[r] ? tb : tn;    // collapse rows: unclamped
            t3[r] = (!br[r] && it >= 3) ? t3[r] : tupd;  // freeze collapse after 3
        }
    }
    #pragma unroll
    for (int r = 0; r < 2; ++r) {
        float q3  = fmaxf(fmaf(t3[r], fmaf(t3[r], A[r], -2.0f * p[r]), N[r]), EPSC);
        float k3  = fmaxf(fsqrt_(q3), 1.0f);
        float inv = frcp(k3);
        res[r] = make_float2(fmaf(-t3[r], ax[r], ux[r]) * inv,
                             fmaf(-t3[r], ay[r], uy[r]) * inv);
    }
}

// branchless easy path; a,b precomputed. returns true if heavy (branch 3).
__device__ __forceinline__ bool easy_row(float ux, float uy,
                                         float ax, float ay, float b,
                                         float& ox, float& oy) {
    float A  = fmaf(ax, ax, ay * ay);
    float p  = fmaf(ax, ux, ay * uy);
    float N  = fmaf(ux, ux, uy * uy);
    float s1 = fminf(1.0f, frsq(fmaxf(N, EPSC)));   // min(1, 1/|u|)
    float u1x = ux * s1, u1y = uy * s1;
    bool feas1 = fmaf(ax, u1x, ay * u1y) <= b + TOLC;
    float t2  = LAMC * (p - b) * frcp(fmaf(LAMC, A, 1.0f));
    float u2x = fmaf(-t2, ax, ux), u2y = fmaf(-t2, ay, uy);
    bool ok2 = (t2 >= -TOLC) && (fmaf(u2x, u2x, u2y * u2y) <= 1.0f + TOLC);
    ox = feas1 ? u1x : u2x;
    oy = feas1 ? u1y : u2y;
    return !feas1 && !ok2;
}

__global__ __launch_bounds__(BLK) void cbf_kernel(const float4* __restrict__ u4,
                                                  const float4* __restrict__ obs4,
                                                  float4* __restrict__ out4,
                                                  int npair) {
    // staged heavy inputs (ux,uy,ax,ay); results written IN-PLACE (xy) after solve
    __shared__ float4 sdat[WPB][RPW];
    __shared__ float  sbv [WPB][RPW];   // staged heavy b

    int tid  = threadIdx.x;
    int wave = tid >> 6;
    int lane = tid & 63;
    unsigned long long ltmask = (1ull << lane) - 1ull;
    int pairbase = blockIdx.x * (BLK * PPT);

    float4 r[PPT];
    bool   hv[2 * PPT];
    bool   valid[PPT];
    float  sx[2 * PPT], sy[2 * PPT], sax[2 * PPT], say[2 * PPT], sb[2 * PPT];

    #pragma unroll
    for (int k = 0; k < PPT; ++k) {
        int i = pairbase + k * BLK + tid;
        valid[k] = i < npair;
        float4 z  = make_float4(0.f, 0.f, 0.f, 0.f);
        float4 uu = valid[k] ? u4[i]           : z;
        float4 o0 = valid[k] ? obs4[3 * i + 0] : z;
        float4 o1 = valid[k] ? obs4[3 * i + 1] : z;
        float4 o2 = valid[k] ? obs4[3 * i + 2] : z;
        // row 2i:   p=(o0.z,o0.w)  v=(o1.x,o1.y)
        // row 2i+1: p=(o2.x,o2.y)  v=(o2.z,o2.w)
        float ax0 = -2.0f * o0.z, ay0 = -2.0f * o0.w;
        float b0  = fmaf(2.0f, fmaf(o0.z, o0.z, o0.w * o0.w) - 1.0f,
                         -2.0f * fmaf(o0.z, o1.x, o0.w * o1.y));
        float ax1 = -2.0f * o2.x, ay1 = -2.0f * o2.y;
        float b1  = fmaf(2.0f, fmaf(o2.x, o2.x, o2.y * o2.y) - 1.0f,
                         -2.0f * fmaf(o2.x, o2.z, o2.y * o2.w));
        r[k] = z;
        hv[2 * k]     = valid[k] && easy_row(uu.x, uu.y, ax0, ay0, b0, r[k].x, r[k].y);
        hv[2 * k + 1] = valid[k] && easy_row(uu.z, uu.w, ax1, ay1, b1, r[k].z, r[k].w);
        sx[2 * k] = uu.x;  sy[2 * k] = uu.y;  sax[2 * k] = ax0;  say[2 * k] = ay0;  sb[2 * k] = b0;
        sx[2*k+1] = uu.z;  sy[2*k+1] = uu.w;  sax[2*k+1] = ax1;  say[2*k+1] = ay1;  sb[2*k+1] = b1;
    }

    // wave-local ballot compaction; inputs staged into LDS (no global re-reads)
    int tot = 0;
    int slot[2 * PPT];
    #pragma unroll
    for (int m = 0; m < 2 * PPT; ++m) {
        unsigned long long mm = __ballot(hv[m]);
        slot[m] = tot + __popcll(mm & ltmask);
        if (hv[m]) {
            sdat[wave][slot[m]] = make_float4(sx[m], sy[m], sax[m], say[m]);
            sbv [wave][slot[m]] = sb[m];
        }
        tot += __popcll(mm);
    }
    __threadfence_block();   // wave lockstep + lgkmcnt drain orders LDS w->r

    // heavy batches: 2 rows per lane, interleaved chains. Usually ONE batch
    // (mean tot ~115 < 128). Batch b writes rows [base,base+128) in-place;
    // a later batch reads a disjoint range -> no hazard.
    #pragma unroll 1
    for (int base = 0; base < tot; base += 128) {
        float hux[2], huy[2], hax[2], hay[2], hbb[2];
        float2 hres[2];
        int jj[2];
        #pragma unroll
        for (int q = 0; q < 2; ++q) {
            int j  = base + q * 64 + lane;
            jj[q]  = j;
            int js = (j < tot) ? j : (tot - 1);   // clamp: duplicate work, no store
            float4 d = sdat[wave][js];
            hux[q] = d.x;  huy[q] = d.y;  hax[q] = d.z;  hay[q] = d.w;
            hbb[q] = sbv[wave][js];
        }
        heavy_solve2(hux, huy, hax, hay, hbb, hres);
        #pragma unroll
        for (int q = 0; q < 2; ++q)
            if (jj[q] < tot) *(float2*)&sdat[wave][jj[q]] = hres[q];
    }
    __threadfence_block();

    #pragma unroll
    for (int m = 0; m < 2 * PPT; ++m) {
        if (hv[m]) {
            float2 s = *(const float2*)&sdat[wave][slot[m]];
            int k = m >> 1;
            if (m & 1) { r[k].z = s.x; r[k].w = s.y; }
            else       { r[k].x = s.x; r[k].y = s.y; }
        }
    }
    #pragma unroll
    for (int k = 0; k < PPT; ++k) {
        int i = pairbase + k * BLK + tid;
        if (valid[k]) out4[i] = r[k];
    }
}

extern "C" void kernel_launch(void* const* d_in, const int* in_sizes, int n_in,
                              void* d_out, int out_size, void* d_ws, size_t ws_size,
                              hipStream_t stream) {
    const float* u_nom = (const float*)d_in[0];
    const float* obs   = (const float*)d_in[1];
    float* out = (float*)d_out;
    int rows   = in_sizes[0] / 2;             // B
    int npair  = rows / 2;                    // 2 rows per thread-slot
    int blocks = (npair + BLK * PPT - 1) / (BLK * PPT);
    cbf_kernel<<<blocks, BLK, 0, stream>>>((const float4*)u_nom,
                                           (const float4*)obs,
                                           (float4*)out, npair);
}